// Round 15
// baseline (466.730 us; speedup 1.0000x reference)
//
#include <hip/hip_runtime.h>
#include <hip/hip_bf16.h>
#include <math.h>

#define H 256
#define EDIM 6
#define NEG 0.2f
#define LN_EPS 1e-5f
#define NPAD 20096   // 157 * 128

typedef __bf16 bf16x8 __attribute__((ext_vector_type(8)));
typedef float  floatx4 __attribute__((ext_vector_type(4)));
typedef float  f32x2   __attribute__((ext_vector_type(2)));

__device__ __forceinline__ float b2f(unsigned short u) {
    union { unsigned int i; float f; } v; v.i = ((unsigned int)u) << 16; return v.f;
}
__device__ __forceinline__ unsigned short f2bu(float f) {
    __hip_bfloat16 h = __float2bfloat16(f);
    return *(unsigned short*)&h;
}

// ---------------------------------------------------------------------------
// CSR build
// ---------------------------------------------------------------------------
__global__ void k_edge_hist(const int* __restrict__ ei, int* __restrict__ deg, int E) {
    int e = blockIdx.x * blockDim.x + threadIdx.x;
    if (e >= E) return;
    atomicAdd(&deg[ei[E + e]], 1);
}

// --- hierarchical exclusive scan ---
__global__ __launch_bounds__(256) void k_scan1(const int* __restrict__ deg,
                                               int* __restrict__ row_ptr,
                                               int* __restrict__ bsum, int N) {
    __shared__ int ws[4];
    int tid = threadIdx.x, gid = blockIdx.x * 256 + tid;
    int lane = tid & 63, w = tid >> 6;
    int v = (gid < N) ? deg[gid] : 0;
    int x = v;
#pragma unroll
    for (int d = 1; d < 64; d <<= 1) { int y = __shfl_up(x, d); if (lane >= d) x += y; }
    if (lane == 63) ws[w] = x;
    __syncthreads();
    int off = 0;
#pragma unroll
    for (int i = 0; i < 4; i++) off += (i < w) ? ws[i] : 0;
    if (gid < N) row_ptr[gid] = off + x - v;
    if (tid == 255) bsum[blockIdx.x] = off + x;
}

__global__ __launch_bounds__(256) void k_scan2(int* __restrict__ bsum, int nb) {
    __shared__ int ws[4];
    int tid = threadIdx.x;
    int lane = tid & 63, w = tid >> 6;
    int v = (tid < nb) ? bsum[tid] : 0;
    int x = v;
#pragma unroll
    for (int d = 1; d < 64; d <<= 1) { int y = __shfl_up(x, d); if (lane >= d) x += y; }
    if (lane == 63) ws[w] = x;
    __syncthreads();
    int off = 0;
#pragma unroll
    for (int i = 0; i < 4; i++) off += (i < w) ? ws[i] : 0;
    if (tid < nb) bsum[tid] = off + x - v;
}

__global__ __launch_bounds__(256) void k_scan3(int* __restrict__ row_ptr,
                                               int* __restrict__ cursor,
                                               const int* __restrict__ bsum, int N, int E) {
    int gid = blockIdx.x * 256 + threadIdx.x;
    if (gid < N) {
        int v = row_ptr[gid] + bsum[blockIdx.x];
        row_ptr[gid] = v;
        cursor[gid] = v;
    }
    if (gid == 0) row_ptr[N] = E;
}

// 32B edge record: {src_byte_off into bf16 [N,256] rows (as float bits), ea0..ea5}
__global__ void k_scatter(const int* __restrict__ ei, const float* __restrict__ eattr,
                          int* __restrict__ cursor, float4* __restrict__ erec, int E) {
    int e = blockIdx.x * blockDim.x + threadIdx.x;
    if (e >= E) return;
    int s = ei[e], d = ei[E + e];
    int pos = atomicAdd(&cursor[d], 1);
    float4 ra, rb;
    ra.x = __int_as_float(s << 9);    // byte offset into bf16 [N,256] row (512B)
    ra.y = eattr[e * EDIM + 0];
    ra.z = eattr[e * EDIM + 1];
    ra.w = eattr[e * EDIM + 2];
    rb.x = eattr[e * EDIM + 3];
    rb.y = eattr[e * EDIM + 4];
    rb.z = eattr[e * EDIM + 5];
    rb.w = 0.f;
    erec[(size_t)pos * 2]     = ra;
    erec[(size_t)pos * 2 + 1] = rb;
}

// loop_attr[node][0..5] = mean of incoming edge attrs (layer-invariant)
__global__ __launch_bounds__(256) void k_loop_mean(const int* __restrict__ row_ptr,
                                                   const float4* __restrict__ erec,
                                                   float* __restrict__ loop_attr, int N) {
    int wv = threadIdx.x >> 6, lane = threadIdx.x & 63;
    int node = blockIdx.x * 4 + wv;
    if (node >= N) return;
    int e0 = row_ptr[node], e1 = row_ptr[node + 1];
    float es[6] = {0.f, 0.f, 0.f, 0.f, 0.f, 0.f};
    for (int e = e0 + lane; e < e1; e += 64) {
        float4 ra = erec[(size_t)e * 2];
        float4 rb = erec[(size_t)e * 2 + 1];
        es[0] += ra.y; es[1] += ra.z; es[2] += ra.w;
        es[3] += rb.x; es[4] += rb.y; es[5] += rb.z;
    }
#pragma unroll
    for (int d = 1; d < 64; d <<= 1) {
#pragma unroll
        for (int k = 0; k < 6; k++) es[k] += __shfl_xor(es[k], d);
    }
    if (lane == 0) {
        float inv = 1.f / fmaxf((float)(e1 - e0), 1.f);
        float4 a, b;
        a.x = es[0] * inv; a.y = es[1] * inv; a.z = es[2] * inv; a.w = es[3] * inv;
        b.x = es[4] * inv; b.y = es[5] * inv; b.z = 0.f; b.w = 0.f;
        *(float4*)&loop_attr[(size_t)node * 8]     = a;
        *(float4*)&loop_attr[(size_t)node * 8 + 4] = b;
    }
}

// ---------------------------------------------------------------------------
// All weight/input conversions to bf16 + ALL buffer zeroing in ONE kernel
// ---------------------------------------------------------------------------
__global__ __launch_bounds__(256) void k_conv_all(
    const float* __restrict__ x, const float* __restrict__ Wl0,
    const float* __restrict__ Wr0, const float* __restrict__ Wl,
    const float* __restrict__ Wr,
    __hip_bfloat16* __restrict__ xb, __hip_bfloat16* __restrict__ w0t,
    __hip_bfloat16* __restrict__ wbig, int* __restrict__ deg,
    float* __restrict__ pooled, unsigned int* __restrict__ hbpad, int N) {
    int idx = blockIdx.x * 256 + threadIdx.x;
    const int XN = NPAD * 32;
    if (idx < XN) {
        int r = idx >> 5, k = idx & 31;
        float v = (r < N && k < 23) ? x[r * 23 + k] : 0.f;
        xb[idx] = __float2bfloat16(v);
        return;
    }
    idx -= XN;
    if (idx < 16384) {
        int mat = idx >> 13, rem = idx & 8191;
        int c = rem >> 5, k = rem & 31;
        const float* W = mat ? Wr0 : Wl0;
        float v = (k < 23) ? W[k * 256 + c] : 0.f;
        w0t[idx] = __float2bfloat16(v);
        return;
    }
    idx -= 16384;
    if (idx < 6 * 65536) {
        int mat = idx >> 16, rem = idx & 65535;
        int c = rem >> 8, k = rem & 255;
        const float* W = (mat < 3) ? (Wl + (size_t)mat * 65536)
                       : (Wr + (size_t)(mat - 3) * 65536);
        wbig[idx] = __float2bfloat16(W[k * 256 + c]);
        return;
    }
    idx -= 6 * 65536;
    if (idx < N) { deg[idx] = 0; return; }
    idx -= N;
    if (idx < 16384) { pooled[idx] = 0.f; return; }
    idx -= 16384;
    if (idx < (NPAD - 20000) * 128) hbpad[idx] = 0u;  // hb pad rows (uint = 2 bf16)
}

// ---------------------------------------------------------------------------
// MFMA dual GEMM (r12-proven staged version). K=32: direct-from-global.
// K=256: LDS-staged via global_load_lds width=16, 128x128 tile, BK=32.
// mat0 output -> bf16 (hlb); mat1 -> fp32 (hr).
// ---------------------------------------------------------------------------
template<int K>
__global__ __launch_bounds__(256) void k_gemm_mfma(
    const __hip_bfloat16* __restrict__ A, int N,
    const __hip_bfloat16* __restrict__ Wt1, const float* __restrict__ b1,
    unsigned short* __restrict__ C1,
    const __hip_bfloat16* __restrict__ Wt2, const float* __restrict__ b2,
    float* __restrict__ C2) {
    int tid = threadIdx.x;
    int wv = tid >> 6, lane = tid & 63;
    int quad = lane >> 4, l16 = lane & 15;
    int mat = blockIdx.x >> 1;
    int c0 = (blockIdx.x & 1) * 128;
    int r0 = blockIdx.y * 128;
    const __hip_bfloat16* Wt = mat ? Wt2 : Wt1;
    const float* bv = mat ? b2 : b1;
    int wm = wv >> 1, wn = wv & 1;
    int rbase = r0 + wm * 64;
    int cbase = c0 + wn * 64;

    floatx4 acc[4][4] = {};
    const __bf16* Ab = (const __bf16*)A;
    const __bf16* Bb = (const __bf16*)Wt;

    if constexpr (K == 32) {
        bf16x8 a[4], b[4];
        const __bf16* Ap = Ab + (size_t)(rbase + l16) * K + quad * 8;
#pragma unroll
        for (int mi = 0; mi < 4; mi++)
            a[mi] = *(const bf16x8*)(Ap + (size_t)mi * 16 * K);
        const __bf16* Bp = Bb + (size_t)(cbase + l16) * K + quad * 8;
#pragma unroll
        for (int ni = 0; ni < 4; ni++)
            b[ni] = *(const bf16x8*)(Bp + (size_t)ni * 16 * K);
#pragma unroll
        for (int mi = 0; mi < 4; mi++)
#pragma unroll
            for (int ni = 0; ni < 4; ni++)
                acc[mi][ni] = __builtin_amdgcn_mfma_f32_16x16x32_bf16(a[mi], b[ni], acc[mi][ni], 0, 0, 0);
    } else {
        __shared__ __align__(16) __bf16 As[128 * 32];   // 8 KB
        __shared__ __align__(16) __bf16 Bs[128 * 32];   // 8 KB
        int srow = wv * 16 + (lane >> 2);
        int sseg = lane & 3;
        for (int k0 = 0; k0 < K; k0 += 32) {
#pragma unroll
            for (int j = 0; j < 2; j++) {
                int row = j * 64 + srow;
                const __bf16* gA = Ab + (size_t)(r0 + row) * K + k0 + sseg * 8;
                __builtin_amdgcn_global_load_lds(
                    (const __attribute__((address_space(1))) void*)gA,
                    (__attribute__((address_space(3))) void*)(As + j * 2048 + wv * 512),
                    16, 0, 0);
                const __bf16* gB = Bb + (size_t)(c0 + row) * K + k0 + sseg * 8;
                __builtin_amdgcn_global_load_lds(
                    (const __attribute__((address_space(1))) void*)gB,
                    (__attribute__((address_space(3))) void*)(Bs + j * 2048 + wv * 512),
                    16, 0, 0);
            }
            __syncthreads();
            bf16x8 a[4], b[4];
#pragma unroll
            for (int mi = 0; mi < 4; mi++)
                a[mi] = *(const bf16x8*)(As + (wm * 64 + mi * 16 + l16) * 32 + quad * 8);
#pragma unroll
            for (int ni = 0; ni < 4; ni++)
                b[ni] = *(const bf16x8*)(Bs + (wn * 64 + ni * 16 + l16) * 32 + quad * 8);
#pragma unroll
            for (int mi = 0; mi < 4; mi++)
#pragma unroll
                for (int ni = 0; ni < 4; ni++)
                    acc[mi][ni] = __builtin_amdgcn_mfma_f32_16x16x32_bf16(a[mi], b[ni], acc[mi][ni], 0, 0, 0);
            __syncthreads();
        }
    }
#pragma unroll
    for (int ni = 0; ni < 4; ni++) {
        int c = cbase + ni * 16 + l16;
        float bb = bv[c];
#pragma unroll
        for (int mi = 0; mi < 4; mi++) {
#pragma unroll
            for (int r = 0; r < 4; r++) {
                int gr = rbase + mi * 16 + quad * 4 + r;
                if (gr >= N) continue;
                float val = acc[mi][ni][r] + bb;
                if (mat == 0) C1[(size_t)gr * H + c] = f2bu(val);
                else          C2[(size_t)gr * H + c] = val;
            }
        }
    }
}

// ---------------------------------------------------------------------------
// Fused GATv2 edge pass: 128-thread blocks = 2 waves = 2 INDEPENDENT nodes.
// Doubles per-CU wave ceiling vs 64-thread blocks (16 wg/CU HW limit) while
// keeping retirement coupling at 2 nodes. bf16 gathers (512B/edge row).
// ---------------------------------------------------------------------------
__global__ __launch_bounds__(128) void k_gat(
    const unsigned short* __restrict__ hlb, const float* __restrict__ hr,
    const int* __restrict__ row_ptr, const float4* __restrict__ erec,
    const float* __restrict__ loop_attr,
    const float* __restrict__ We, const float* __restrict__ attv,
    const float* __restrict__ bias, const float* __restrict__ lnw,
    const float* __restrict__ lnb, unsigned short* __restrict__ hout, int N) {
    int lane = threadIdx.x & 63;
    int node = blockIdx.x * 2 + (threadIdx.x >> 6);
    if (node >= N) return;
    int cb = lane * 4;
    int cb2 = lane * 8;               // byte offset within bf16 row
    const char* hbase = (const char*)hlb;
    bool b0 = (lane & 1) != 0;
    bool b1 = (lane & 2) != 0;

    f32x2 we2[EDIM][2];
#pragma unroll
    for (int k = 0; k < EDIM; k++) {
        float4 t = *(const float4*)&We[k * H + cb];
        we2[k][0] = (f32x2){t.x, t.y};
        we2[k][1] = (f32x2){t.z, t.w};
    }
    float4 t;
    t = *(const float4*)&attv[cb];
    f32x2 av0 = {t.x, t.y}, av1 = {t.z, t.w};
    t = *(const float4*)&hr[(size_t)node * H + cb];
    f32x2 hr0 = {t.x, t.y}, hr1 = {t.z, t.w};
    ushort4 hu = *(const ushort4*)&hlb[(size_t)node * H + cb];
    f32x2 hl0 = {b2f(hu.x), b2f(hu.y)}, hl1 = {b2f(hu.z), b2f(hu.w)};

    float denom = 0.f;
    f32x2 acc0 = {0.f, 0.f}, acc1 = {0.f, 0.f};

    int e0 = row_ptr[node], e1 = row_ptr[node + 1];
    int deg = e1 - e0;
    int gfull = deg >> 2;

    for (int g = 0; g <= gfull; g++) {
        int trem = (g == gfull) ? (deg & 3) : 4;
        if (trem == 0) break;
        int base = e0 + g * 4;
        f32x2 hsa[4], hsb[4];
        float p[4];
#pragma unroll
        for (int i = 0; i < 4; i++) {
            int idx = (i < trem) ? (base + i) : base;
            float4 ra = erec[(size_t)idx * 2];
            float4 rb = erec[(size_t)idx * 2 + 1];
            ushort4 u4 = *(const ushort4*)(hbase + (__float_as_int(ra.x) + cb2));
            hsa[i] = (f32x2){b2f(u4.x), b2f(u4.y)};
            hsb[i] = (f32x2){b2f(u4.z), b2f(u4.w)};
            f32x2 t0 = hr0, t1 = hr1;
            t0 += ra.y * we2[0][0]; t1 += ra.y * we2[0][1];
            t0 += ra.z * we2[1][0]; t1 += ra.z * we2[1][1];
            t0 += ra.w * we2[2][0]; t1 += ra.w * we2[2][1];
            t0 += rb.x * we2[3][0]; t1 += rb.x * we2[3][1];
            t0 += rb.y * we2[4][0]; t1 += rb.y * we2[4][1];
            t0 += rb.z * we2[5][0]; t1 += rb.z * we2[5][1];
            f32x2 v0 = hsa[i] + t0;
            f32x2 v1 = hsb[i] + t1;
            v0 = __builtin_elementwise_max(v0, v0 * NEG);
            v1 = __builtin_elementwise_max(v1, v1 * NEG);
            f32x2 pd = v0 * av0;
            pd += v1 * av1;
            p[i] = pd.x + pd.y;
        }
        // 4-value all-reduce: fold to one value/lane, butterfly, expand
        float a01 = b0 ? p[1] : p[0];
        float c01 = b0 ? p[0] : p[1];
        a01 += __shfl_xor(c01, 1);
        float a23 = b0 ? p[3] : p[2];
        float c23 = b0 ? p[2] : p[3];
        a23 += __shfl_xor(c23, 1);
        float u = b1 ? a23 : a01;
        float v = b1 ? a01 : a23;
        u += __shfl_xor(v, 2);
        u += __shfl_xor(u, 4);
        u += __shfl_xor(u, 8);
        u += __shfl_xor(u, 16);
        u += __shfl_xor(u, 32);
        float w = ((lane & 3) < trem) ? __expf(u) : 0.f;
        float wx1 = __shfl_xor(w, 1);
        float wx2 = __shfl_xor(w, 2);
        float wx3 = __shfl_xor(wx1, 2);
        denom += (w + wx1) + (wx2 + wx3);
        float x0 = b0 ? wx1 : w,   x1 = b0 ? w   : wx1;
        float x2 = b0 ? wx3 : wx2, x3 = b0 ? wx2 : wx3;
        float w0 = b1 ? x2 : x0, w1 = b1 ? x3 : x1;
        float w2 = b1 ? x0 : x2, w3 = b1 ? x1 : x3;
        acc0 += w0 * hsa[0]; acc1 += w0 * hsb[0];
        acc0 += w1 * hsa[1]; acc1 += w1 * hsb[1];
        acc0 += w2 * hsa[2]; acc1 += w2 * hsb[2];
        acc0 += w3 * hsa[3]; acc1 += w3 * hsb[3];
    }

    // self loop with precomputed mean attrs
    {
        float4 la0 = *(const float4*)&loop_attr[(size_t)node * 8];
        float4 la1 = *(const float4*)&loop_attr[(size_t)node * 8 + 4];
        f32x2 t0 = hl0 + hr0, t1 = hl1 + hr1;
        t0 += la0.x * we2[0][0]; t1 += la0.x * we2[0][1];
        t0 += la0.y * we2[1][0]; t1 += la0.y * we2[1][1];
        t0 += la0.z * we2[2][0]; t1 += la0.z * we2[2][1];
        t0 += la0.w * we2[3][0]; t1 += la0.w * we2[3][1];
        t0 += la1.x * we2[4][0]; t1 += la1.x * we2[4][1];
        t0 += la1.y * we2[5][0]; t1 += la1.y * we2[5][1];
        t0 = __builtin_elementwise_max(t0, t0 * NEG);
        t1 = __builtin_elementwise_max(t1, t1 * NEG);
        f32x2 pd = t0 * av0;
        pd += t1 * av1;
        float p = pd.x + pd.y;
#pragma unroll
        for (int d = 1; d < 64; d <<= 1) p += __shfl_xor(p, d);
        float w = __expf(p);
        denom += w;
        acc0 += w * hl0; acc1 += w * hl1;
    }

    float inv = 1.f / denom;
    t = *(const float4*)&bias[cb];
    float o0 = acc0.x * inv + t.x;
    float o1 = acc0.y * inv + t.y;
    float o2 = acc1.x * inv + t.z;
    float o3 = acc1.y * inv + t.w;

    // fused LN reduce: sum and sum-of-squares together (k=2 trick)
    float s = (o0 + o1) + (o2 + o3);
    float q = fmaf(o0, o0, fmaf(o1, o1, fmaf(o2, o2, o3 * o3)));
    float a = b0 ? q : s;
    float c = b0 ? s : q;
    a += __shfl_xor(c, 1);
    a += __shfl_xor(a, 2);
    a += __shfl_xor(a, 4);
    a += __shfl_xor(a, 8);
    a += __shfl_xor(a, 16);
    a += __shfl_xor(a, 32);
    float other = __shfl_xor(a, 1);
    float stot = b0 ? other : a;
    float qtot = b0 ? a : other;
    float mu = stot * (1.f / 256.f);
    float var = fmaf(-mu, mu, qtot * (1.f / 256.f));
    float rstd = rsqrtf(fmaxf(var, 0.f) + LN_EPS);

    float4 w4 = *(const float4*)&lnw[cb];
    float4 b4 = *(const float4*)&lnb[cb];
    ushort4 outv;
    outv.x = f2bu(fmaxf((o0 - mu) * rstd * w4.x + b4.x, 0.f));
    outv.y = f2bu(fmaxf((o1 - mu) * rstd * w4.y + b4.y, 0.f));
    outv.z = f2bu(fmaxf((o2 - mu) * rstd * w4.z + b4.z, 0.f));
    outv.w = f2bu(fmaxf((o3 - mu) * rstd * w4.w + b4.w, 0.f));
    *(ushort4*)&hout[(size_t)node * H + cb] = outv;
}

// ---------------------------------------------------------------------------
// Pool BEFORE projection (linearity reorder). Stage 1: segmented atomic sums.
// ---------------------------------------------------------------------------
__global__ __launch_bounds__(256) void k_pool_sum(
    const unsigned short* __restrict__ hb, const int* __restrict__ batch,
    float* __restrict__ pooled, int N) {
    int c = threadIdx.x;
    int chunk = (N + gridDim.x - 1) / gridDim.x;
    int n0 = blockIdx.x * chunk;
    int n1 = min(n0 + chunk, N);
    if (n0 >= n1) return;
    float acc = 0.f;
    int cur = batch[n0];
    for (int n = n0; n < n1; n++) {
        int g = batch[n];
        if (g != cur) {
            atomicAdd(&pooled[cur * H + c], acc);
            acc = 0.f; cur = g;
        }
        acc += b2f(hb[(size_t)n * H + c]);
    }
    atomicAdd(&pooled[cur * H + c], acc);
}

// Stage 2: out[g] = (pooled[g]/cnt) @ lin_W + lin_b
__global__ __launch_bounds__(256) void k_lin_pool(
    const float* __restrict__ pooled, const int* __restrict__ batch,
    const float* __restrict__ linW, const float* __restrict__ linb,
    float* __restrict__ out, int N) {
    __shared__ float row[H];
    __shared__ int s_lo, s_hi;
    int g = blockIdx.x, c = threadIdx.x;
    if (c == 0) {
        int lo = 0, hi = N;
        while (lo < hi) { int mid = (lo + hi) >> 1; if (batch[mid] < g) lo = mid + 1; else hi = mid; }
        s_lo = lo;
    }
    if (c == 1) {
        int lo = 0, hi = N;
        while (lo < hi) { int mid = (lo + hi) >> 1; if (batch[mid] < g + 1) lo = mid + 1; else hi = mid; }
        s_hi = lo;
    }
    __syncthreads();
    int cnt = s_hi - s_lo;
    float scale = (cnt > 0) ? 1.f / (float)cnt : 0.f;
    row[c] = pooled[g * H + c] * scale;
    __syncthreads();
    float acc = (cnt > 0) ? linb[c] : 0.f;
#pragma unroll 8
    for (int k = 0; k < H; k++) acc = fmaf(row[k], linW[k * H + c], acc);
    out[g * H + c] = acc;
}

// ---------------------------------------------------------------------------
extern "C" void kernel_launch(void* const* d_in, const int* in_sizes, int n_in,
                              void* d_out, int out_size, void* d_ws, size_t ws_size,
                              hipStream_t stream) {
    const float* x        = (const float*)d_in[0];
    const int*   ei       = (const int*)d_in[1];
    const float* eattr    = (const float*)d_in[2];
    const int*   batch    = (const int*)d_in[3];
    const float* W_l0     = (const float*)d_in[4];
    const float* W_r0     = (const float*)d_in[5];
    const float* W_l      = (const float*)d_in[6];
    const float* W_r      = (const float*)d_in[7];
    const float* b_l      = (const float*)d_in[8];
    const float* b_r      = (const float*)d_in[9];
    const float* W_e      = (const float*)d_in[10];
    const float* att      = (const float*)d_in[11];
    const float* bias     = (const float*)d_in[12];
    const float* ln_w     = (const float*)d_in[13];
    const float* ln_b     = (const float*)d_in[14];
    const float* lin_W    = (const float*)d_in[15];
    const float* lin_b    = (const float*)d_in[16];

    const int N = in_sizes[0] / 23;          // 20000
    const int E = in_sizes[1] / 2;           // 320000
    const int G = out_size / H;              // 64
    const int L = 4;

    // workspace layout
    char* p = (char*)d_ws;
    unsigned short* hlb = (unsigned short*)p;     p += (size_t)N * H * 2;
    float* hr  = (float*)p;                       p += (size_t)N * H * 4;
    float4* erec = (float4*)p;                    p += (size_t)E * 32;
    unsigned short* hb = (unsigned short*)p;      p += (size_t)NPAD * H * 2;
    __hip_bfloat16* xb  = (__hip_bfloat16*)p;     p += (size_t)NPAD * 32 * 2;
    __hip_bfloat16* w0t = (__hip_bfloat16*)p;     p += (size_t)2 * 256 * 32 * 2;
    __hip_bfloat16* wbig = (__hip_bfloat16*)p;    p += (size_t)6 * 65536 * 2;
    float* loop_attr = (float*)p;                 p += (size_t)N * 8 * 4;
    float* pooled = (float*)p;                    p += (size_t)G * H * 4;
    int* deg      = (int*)p;                      p += (size_t)N * 4;
    int* row_ptr  = (int*)p;                      p += (size_t)(N + 1) * 4;
    int* cursor   = (int*)p;                      p += (size_t)N * 4;
    int* bsum     = (int*)p;                      p += (size_t)256 * 4;

    __hip_bfloat16* Wl0t = w0t;
    __hip_bfloat16* Wr0t = w0t + 8192;
    __hip_bfloat16* Wlt  = wbig;
    __hip_bfloat16* Wrt  = wbig + (size_t)3 * 65536;

    int tb = 256;
    int conv_total = NPAD * 32 + 16384 + 6 * 65536 + N + 16384 + (NPAD - N) * 128;
    k_conv_all<<<(conv_total + tb - 1) / tb, tb, 0, stream>>>(
        x, W_l0, W_r0, W_l, W_r, xb, w0t, wbig, deg, pooled,
        (unsigned int*)(hb + (size_t)N * H), N);

    k_edge_hist<<<(E + tb - 1) / tb, tb, 0, stream>>>(ei, deg, E);
    int nb = (N + 255) / 256;
    k_scan1<<<nb, 256, 0, stream>>>(deg, row_ptr, bsum, N);
    k_scan2<<<1, 256, 0, stream>>>(bsum, nb);
    k_scan3<<<nb, 256, 0, stream>>>(row_ptr, cursor, bsum, N, E);
    k_scatter<<<(E + tb - 1) / tb, tb, 0, stream>>>(ei, eattr, cursor, erec, E);
    k_loop_mean<<<(N + 3) / 4, 256, 0, stream>>>(row_ptr, erec, loop_attr, N);

    dim3 gdual(4, NPAD / 128), blk(256);

    for (int l = 0; l < L; l++) {
        const __hip_bfloat16* A  = (l == 0) ? xb : (const __hip_bfloat16*)hb;
        const __hip_bfloat16* Wl = (l == 0) ? Wl0t : (Wlt + (size_t)(l - 1) * 65536);
        const __hip_bfloat16* Wr = (l == 0) ? Wr0t : (Wrt + (size_t)(l - 1) * 65536);
        if (l == 0)
            k_gemm_mfma<32><<<gdual, blk, 0, stream>>>(A, N, Wl, b_l + l * H, hlb,
                                                       Wr, b_r + l * H, hr);
        else
            k_gemm_mfma<256><<<gdual, blk, 0, stream>>>(A, N, Wl, b_l + l * H, hlb,
                                                        Wr, b_r + l * H, hr);
        k_gat<<<(N + 1) / 2, 128, 0, stream>>>(hlb, hr, row_ptr, erec, loop_attr,
                                               W_e + (size_t)l * EDIM * H, att + l * H,
                                               bias + l * H, ln_w + l * H, ln_b + l * H, hb, N);
    }

    // pool-then-project (linearity reorder): mean(h) @ lin_W + lin_b
    k_pool_sum<<<256, 256, 0, stream>>>(hb, batch, pooled, N);
    k_lin_pool<<<G, 256, 0, stream>>>(pooled, batch, lin_W, lin_b, (float*)d_out, N);
}

// Round 16
// 427.964 us; speedup vs baseline: 1.0906x; 1.0906x over previous
//
#include <hip/hip_runtime.h>
#include <hip/hip_bf16.h>
#include <math.h>

#define H 256
#define EDIM 6
#define NEG 0.2f
#define LN_EPS 1e-5f
#define NPAD 20096   // 157 * 128

typedef __bf16 bf16x8 __attribute__((ext_vector_type(8)));
typedef float  floatx4 __attribute__((ext_vector_type(4)));
typedef float  f32x2   __attribute__((ext_vector_type(2)));

__device__ __forceinline__ float b2f(unsigned short u) {
    union { unsigned int i; float f; } v; v.i = ((unsigned int)u) << 16; return v.f;
}
__device__ __forceinline__ unsigned short f2bu(float f) {
    __hip_bfloat16 h = __float2bfloat16(f);
    return *(unsigned short*)&h;
}

// ---------------------------------------------------------------------------
// CSR build
// ---------------------------------------------------------------------------
__global__ void k_edge_hist(const int* __restrict__ ei, int* __restrict__ deg, int E) {
    int e = blockIdx.x * blockDim.x + threadIdx.x;
    if (e >= E) return;
    atomicAdd(&deg[ei[E + e]], 1);
}

// --- hierarchical exclusive scan ---
__global__ __launch_bounds__(256) void k_scan1(const int* __restrict__ deg,
                                               int* __restrict__ row_ptr,
                                               int* __restrict__ bsum, int N) {
    __shared__ int ws[4];
    int tid = threadIdx.x, gid = blockIdx.x * 256 + tid;
    int lane = tid & 63, w = tid >> 6;
    int v = (gid < N) ? deg[gid] : 0;
    int x = v;
#pragma unroll
    for (int d = 1; d < 64; d <<= 1) { int y = __shfl_up(x, d); if (lane >= d) x += y; }
    if (lane == 63) ws[w] = x;
    __syncthreads();
    int off = 0;
#pragma unroll
    for (int i = 0; i < 4; i++) off += (i < w) ? ws[i] : 0;
    if (gid < N) row_ptr[gid] = off + x - v;
    if (tid == 255) bsum[blockIdx.x] = off + x;
}

__global__ __launch_bounds__(256) void k_scan2(int* __restrict__ bsum, int nb) {
    __shared__ int ws[4];
    int tid = threadIdx.x;
    int lane = tid & 63, w = tid >> 6;
    int v = (tid < nb) ? bsum[tid] : 0;
    int x = v;
#pragma unroll
    for (int d = 1; d < 64; d <<= 1) { int y = __shfl_up(x, d); if (lane >= d) x += y; }
    if (lane == 63) ws[w] = x;
    __syncthreads();
    int off = 0;
#pragma unroll
    for (int i = 0; i < 4; i++) off += (i < w) ? ws[i] : 0;
    if (tid < nb) bsum[tid] = off + x - v;
}

__global__ __launch_bounds__(256) void k_scan3(int* __restrict__ row_ptr,
                                               int* __restrict__ cursor,
                                               const int* __restrict__ bsum, int N, int E) {
    int gid = blockIdx.x * 256 + threadIdx.x;
    if (gid < N) {
        int v = row_ptr[gid] + bsum[blockIdx.x];
        row_ptr[gid] = v;
        cursor[gid] = v;
    }
    if (gid == 0) row_ptr[N] = E;
}

// 32B edge record: {src_byte_off into bf16 [N,256] rows (as float bits), ea0..ea5}
__global__ void k_scatter(const int* __restrict__ ei, const float* __restrict__ eattr,
                          int* __restrict__ cursor, float4* __restrict__ erec, int E) {
    int e = blockIdx.x * blockDim.x + threadIdx.x;
    if (e >= E) return;
    int s = ei[e], d = ei[E + e];
    int pos = atomicAdd(&cursor[d], 1);
    float4 ra, rb;
    ra.x = __int_as_float(s << 9);    // byte offset into bf16 [N,256] row (512B)
    ra.y = eattr[e * EDIM + 0];
    ra.z = eattr[e * EDIM + 1];
    ra.w = eattr[e * EDIM + 2];
    rb.x = eattr[e * EDIM + 3];
    rb.y = eattr[e * EDIM + 4];
    rb.z = eattr[e * EDIM + 5];
    rb.w = 0.f;
    erec[(size_t)pos * 2]     = ra;
    erec[(size_t)pos * 2 + 1] = rb;
}

// loop_attr[node][0..5] = mean of incoming edge attrs (layer-invariant)
__global__ __launch_bounds__(256) void k_loop_mean(const int* __restrict__ row_ptr,
                                                   const float4* __restrict__ erec,
                                                   float* __restrict__ loop_attr, int N) {
    int wv = threadIdx.x >> 6, lane = threadIdx.x & 63;
    int node = blockIdx.x * 4 + wv;
    if (node >= N) return;
    int e0 = row_ptr[node], e1 = row_ptr[node + 1];
    float es[6] = {0.f, 0.f, 0.f, 0.f, 0.f, 0.f};
    for (int e = e0 + lane; e < e1; e += 64) {
        float4 ra = erec[(size_t)e * 2];
        float4 rb = erec[(size_t)e * 2 + 1];
        es[0] += ra.y; es[1] += ra.z; es[2] += ra.w;
        es[3] += rb.x; es[4] += rb.y; es[5] += rb.z;
    }
#pragma unroll
    for (int d = 1; d < 64; d <<= 1) {
#pragma unroll
        for (int k = 0; k < 6; k++) es[k] += __shfl_xor(es[k], d);
    }
    if (lane == 0) {
        float inv = 1.f / fmaxf((float)(e1 - e0), 1.f);
        float4 a, b;
        a.x = es[0] * inv; a.y = es[1] * inv; a.z = es[2] * inv; a.w = es[3] * inv;
        b.x = es[4] * inv; b.y = es[5] * inv; b.z = 0.f; b.w = 0.f;
        *(float4*)&loop_attr[(size_t)node * 8]     = a;
        *(float4*)&loop_attr[(size_t)node * 8 + 4] = b;
    }
}

// ---------------------------------------------------------------------------
// All weight/input conversions to bf16 + ALL buffer zeroing in ONE kernel
// ---------------------------------------------------------------------------
__global__ __launch_bounds__(256) void k_conv_all(
    const float* __restrict__ x, const float* __restrict__ Wl0,
    const float* __restrict__ Wr0, const float* __restrict__ Wl,
    const float* __restrict__ Wr,
    __hip_bfloat16* __restrict__ xb, __hip_bfloat16* __restrict__ w0t,
    __hip_bfloat16* __restrict__ wbig, int* __restrict__ deg,
    float* __restrict__ pooled, unsigned int* __restrict__ hbpad, int N) {
    int idx = blockIdx.x * 256 + threadIdx.x;
    const int XN = NPAD * 32;
    if (idx < XN) {
        int r = idx >> 5, k = idx & 31;
        float v = (r < N && k < 23) ? x[r * 23 + k] : 0.f;
        xb[idx] = __float2bfloat16(v);
        return;
    }
    idx -= XN;
    if (idx < 16384) {
        int mat = idx >> 13, rem = idx & 8191;
        int c = rem >> 5, k = rem & 31;
        const float* W = mat ? Wr0 : Wl0;
        float v = (k < 23) ? W[k * 256 + c] : 0.f;
        w0t[idx] = __float2bfloat16(v);
        return;
    }
    idx -= 16384;
    if (idx < 6 * 65536) {
        int mat = idx >> 16, rem = idx & 65535;
        int c = rem >> 8, k = rem & 255;
        const float* W = (mat < 3) ? (Wl + (size_t)mat * 65536)
                       : (Wr + (size_t)(mat - 3) * 65536);
        wbig[idx] = __float2bfloat16(W[k * 256 + c]);
        return;
    }
    idx -= 6 * 65536;
    if (idx < N) { deg[idx] = 0; return; }
    idx -= N;
    if (idx < 16384) { pooled[idx] = 0.f; return; }
    idx -= 16384;
    if (idx < (NPAD - 20000) * 128) hbpad[idx] = 0u;  // hb pad rows (uint = 2 bf16)
}

// ---------------------------------------------------------------------------
// MFMA dual GEMM (r12-proven staged version). K=32: direct-from-global.
// K=256: LDS-staged via global_load_lds width=16, 128x128 tile, BK=32.
// BOTH outputs -> bf16 (hlb, hrb): halves epilogue stores + k_gat reads.
// ---------------------------------------------------------------------------
template<int K>
__global__ __launch_bounds__(256) void k_gemm_mfma(
    const __hip_bfloat16* __restrict__ A, int N,
    const __hip_bfloat16* __restrict__ Wt1, const float* __restrict__ b1,
    unsigned short* __restrict__ C1,
    const __hip_bfloat16* __restrict__ Wt2, const float* __restrict__ b2,
    unsigned short* __restrict__ C2) {
    int tid = threadIdx.x;
    int wv = tid >> 6, lane = tid & 63;
    int quad = lane >> 4, l16 = lane & 15;
    int mat = blockIdx.x >> 1;
    int c0 = (blockIdx.x & 1) * 128;
    int r0 = blockIdx.y * 128;
    const __hip_bfloat16* Wt = mat ? Wt2 : Wt1;
    const float* bv = mat ? b2 : b1;
    unsigned short* C = mat ? C2 : C1;
    int wm = wv >> 1, wn = wv & 1;
    int rbase = r0 + wm * 64;
    int cbase = c0 + wn * 64;

    floatx4 acc[4][4] = {};
    const __bf16* Ab = (const __bf16*)A;
    const __bf16* Bb = (const __bf16*)Wt;

    if constexpr (K == 32) {
        bf16x8 a[4], b[4];
        const __bf16* Ap = Ab + (size_t)(rbase + l16) * K + quad * 8;
#pragma unroll
        for (int mi = 0; mi < 4; mi++)
            a[mi] = *(const bf16x8*)(Ap + (size_t)mi * 16 * K);
        const __bf16* Bp = Bb + (size_t)(cbase + l16) * K + quad * 8;
#pragma unroll
        for (int ni = 0; ni < 4; ni++)
            b[ni] = *(const bf16x8*)(Bp + (size_t)ni * 16 * K);
#pragma unroll
        for (int mi = 0; mi < 4; mi++)
#pragma unroll
            for (int ni = 0; ni < 4; ni++)
                acc[mi][ni] = __builtin_amdgcn_mfma_f32_16x16x32_bf16(a[mi], b[ni], acc[mi][ni], 0, 0, 0);
    } else {
        __shared__ __align__(16) __bf16 As[128 * 32];   // 8 KB
        __shared__ __align__(16) __bf16 Bs[128 * 32];   // 8 KB
        int srow = wv * 16 + (lane >> 2);
        int sseg = lane & 3;
        for (int k0 = 0; k0 < K; k0 += 32) {
#pragma unroll
            for (int j = 0; j < 2; j++) {
                int row = j * 64 + srow;
                const __bf16* gA = Ab + (size_t)(r0 + row) * K + k0 + sseg * 8;
                __builtin_amdgcn_global_load_lds(
                    (const __attribute__((address_space(1))) void*)gA,
                    (__attribute__((address_space(3))) void*)(As + j * 2048 + wv * 512),
                    16, 0, 0);
                const __bf16* gB = Bb + (size_t)(c0 + row) * K + k0 + sseg * 8;
                __builtin_amdgcn_global_load_lds(
                    (const __attribute__((address_space(1))) void*)gB,
                    (__attribute__((address_space(3))) void*)(Bs + j * 2048 + wv * 512),
                    16, 0, 0);
            }
            __syncthreads();
            bf16x8 a[4], b[4];
#pragma unroll
            for (int mi = 0; mi < 4; mi++)
                a[mi] = *(const bf16x8*)(As + (wm * 64 + mi * 16 + l16) * 32 + quad * 8);
#pragma unroll
            for (int ni = 0; ni < 4; ni++)
                b[ni] = *(const bf16x8*)(Bs + (wn * 64 + ni * 16 + l16) * 32 + quad * 8);
#pragma unroll
            for (int mi = 0; mi < 4; mi++)
#pragma unroll
                for (int ni = 0; ni < 4; ni++)
                    acc[mi][ni] = __builtin_amdgcn_mfma_f32_16x16x32_bf16(a[mi], b[ni], acc[mi][ni], 0, 0, 0);
            __syncthreads();
        }
    }
#pragma unroll
    for (int ni = 0; ni < 4; ni++) {
        int c = cbase + ni * 16 + l16;
        float bb = bv[c];
#pragma unroll
        for (int mi = 0; mi < 4; mi++) {
#pragma unroll
            for (int r = 0; r < 4; r++) {
                int gr = rbase + mi * 16 + quad * 4 + r;
                if (gr >= N) continue;
                C[(size_t)gr * H + c] = f2bu(acc[mi][ni][r] + bb);
            }
        }
    }
}

// ---------------------------------------------------------------------------
// Fused GATv2 edge pass (r14-proven): ONE WAVE = ONE BLOCK = ONE NODE.
// bf16 gathers + bf16 hr reads.
// ---------------------------------------------------------------------------
__global__ __launch_bounds__(64) void k_gat(
    const unsigned short* __restrict__ hlb, const unsigned short* __restrict__ hrb,
    const int* __restrict__ row_ptr, const float4* __restrict__ erec,
    const float* __restrict__ loop_attr,
    const float* __restrict__ We, const float* __restrict__ attv,
    const float* __restrict__ bias, const float* __restrict__ lnw,
    const float* __restrict__ lnb, unsigned short* __restrict__ hout, int N) {
    int lane = threadIdx.x & 63;
    int node = blockIdx.x;
    if (node >= N) return;
    int cb = lane * 4;
    int cb2 = lane * 8;               // byte offset within bf16 row
    const char* hbase = (const char*)hlb;
    bool b0 = (lane & 1) != 0;
    bool b1 = (lane & 2) != 0;

    f32x2 we2[EDIM][2];
#pragma unroll
    for (int k = 0; k < EDIM; k++) {
        float4 t = *(const float4*)&We[k * H + cb];
        we2[k][0] = (f32x2){t.x, t.y};
        we2[k][1] = (f32x2){t.z, t.w};
    }
    float4 t;
    t = *(const float4*)&attv[cb];
    f32x2 av0 = {t.x, t.y}, av1 = {t.z, t.w};
    ushort4 hru = *(const ushort4*)&hrb[(size_t)node * H + cb];
    f32x2 hr0 = {b2f(hru.x), b2f(hru.y)}, hr1 = {b2f(hru.z), b2f(hru.w)};
    ushort4 hu = *(const ushort4*)&hlb[(size_t)node * H + cb];
    f32x2 hl0 = {b2f(hu.x), b2f(hu.y)}, hl1 = {b2f(hu.z), b2f(hu.w)};

    float denom = 0.f;
    f32x2 acc0 = {0.f, 0.f}, acc1 = {0.f, 0.f};

    int e0 = row_ptr[node], e1 = row_ptr[node + 1];
    int deg = e1 - e0;
    int gfull = deg >> 2;

    for (int g = 0; g <= gfull; g++) {
        int trem = (g == gfull) ? (deg & 3) : 4;
        if (trem == 0) break;
        int base = e0 + g * 4;
        f32x2 hsa[4], hsb[4];
        float p[4];
#pragma unroll
        for (int i = 0; i < 4; i++) {
            int idx = (i < trem) ? (base + i) : base;
            float4 ra = erec[(size_t)idx * 2];
            float4 rb = erec[(size_t)idx * 2 + 1];
            ushort4 u4 = *(const ushort4*)(hbase + (__float_as_int(ra.x) + cb2));
            hsa[i] = (f32x2){b2f(u4.x), b2f(u4.y)};
            hsb[i] = (f32x2){b2f(u4.z), b2f(u4.w)};
            f32x2 t0 = hr0, t1 = hr1;
            t0 += ra.y * we2[0][0]; t1 += ra.y * we2[0][1];
            t0 += ra.z * we2[1][0]; t1 += ra.z * we2[1][1];
            t0 += ra.w * we2[2][0]; t1 += ra.w * we2[2][1];
            t0 += rb.x * we2[3][0]; t1 += rb.x * we2[3][1];
            t0 += rb.y * we2[4][0]; t1 += rb.y * we2[4][1];
            t0 += rb.z * we2[5][0]; t1 += rb.z * we2[5][1];
            f32x2 v0 = hsa[i] + t0;
            f32x2 v1 = hsb[i] + t1;
            v0 = __builtin_elementwise_max(v0, v0 * NEG);
            v1 = __builtin_elementwise_max(v1, v1 * NEG);
            f32x2 pd = v0 * av0;
            pd += v1 * av1;
            p[i] = pd.x + pd.y;
        }
        // 4-value all-reduce: fold to one value/lane, butterfly, expand
        float a01 = b0 ? p[1] : p[0];
        float c01 = b0 ? p[0] : p[1];
        a01 += __shfl_xor(c01, 1);
        float a23 = b0 ? p[3] : p[2];
        float c23 = b0 ? p[2] : p[3];
        a23 += __shfl_xor(c23, 1);
        float u = b1 ? a23 : a01;
        float v = b1 ? a01 : a23;
        u += __shfl_xor(v, 2);
        u += __shfl_xor(u, 4);
        u += __shfl_xor(u, 8);
        u += __shfl_xor(u, 16);
        u += __shfl_xor(u, 32);
        float w = ((lane & 3) < trem) ? __expf(u) : 0.f;
        float wx1 = __shfl_xor(w, 1);
        float wx2 = __shfl_xor(w, 2);
        float wx3 = __shfl_xor(wx1, 2);
        denom += (w + wx1) + (wx2 + wx3);
        float x0 = b0 ? wx1 : w,   x1 = b0 ? w   : wx1;
        float x2 = b0 ? wx3 : wx2, x3 = b0 ? wx2 : wx3;
        float w0 = b1 ? x2 : x0, w1 = b1 ? x3 : x1;
        float w2 = b1 ? x0 : x2, w3 = b1 ? x1 : x3;
        acc0 += w0 * hsa[0]; acc1 += w0 * hsb[0];
        acc0 += w1 * hsa[1]; acc1 += w1 * hsb[1];
        acc0 += w2 * hsa[2]; acc1 += w2 * hsb[2];
        acc0 += w3 * hsa[3]; acc1 += w3 * hsb[3];
    }

    // self loop with precomputed mean attrs
    {
        float4 la0 = *(const float4*)&loop_attr[(size_t)node * 8];
        float4 la1 = *(const float4*)&loop_attr[(size_t)node * 8 + 4];
        f32x2 t0 = hl0 + hr0, t1 = hl1 + hr1;
        t0 += la0.x * we2[0][0]; t1 += la0.x * we2[0][1];
        t0 += la0.y * we2[1][0]; t1 += la0.y * we2[1][1];
        t0 += la0.z * we2[2][0]; t1 += la0.z * we2[2][1];
        t0 += la0.w * we2[3][0]; t1 += la0.w * we2[3][1];
        t0 += la1.x * we2[4][0]; t1 += la1.x * we2[4][1];
        t0 += la1.y * we2[5][0]; t1 += la1.y * we2[5][1];
        t0 = __builtin_elementwise_max(t0, t0 * NEG);
        t1 = __builtin_elementwise_max(t1, t1 * NEG);
        f32x2 pd = t0 * av0;
        pd += t1 * av1;
        float p = pd.x + pd.y;
#pragma unroll
        for (int d = 1; d < 64; d <<= 1) p += __shfl_xor(p, d);
        float w = __expf(p);
        denom += w;
        acc0 += w * hl0; acc1 += w * hl1;
    }

    float inv = 1.f / denom;
    t = *(const float4*)&bias[cb];
    float o0 = acc0.x * inv + t.x;
    float o1 = acc0.y * inv + t.y;
    float o2 = acc1.x * inv + t.z;
    float o3 = acc1.y * inv + t.w;

    // fused LN reduce: sum and sum-of-squares together (k=2 trick)
    float s = (o0 + o1) + (o2 + o3);
    float q = fmaf(o0, o0, fmaf(o1, o1, fmaf(o2, o2, o3 * o3)));
    float a = b0 ? q : s;
    float c = b0 ? s : q;
    a += __shfl_xor(c, 1);
    a += __shfl_xor(a, 2);
    a += __shfl_xor(a, 4);
    a += __shfl_xor(a, 8);
    a += __shfl_xor(a, 16);
    a += __shfl_xor(a, 32);
    float other = __shfl_xor(a, 1);
    float stot = b0 ? other : a;
    float qtot = b0 ? a : other;
    float mu = stot * (1.f / 256.f);
    float var = fmaf(-mu, mu, qtot * (1.f / 256.f));
    float rstd = rsqrtf(fmaxf(var, 0.f) + LN_EPS);

    float4 w4 = *(const float4*)&lnw[cb];
    float4 b4 = *(const float4*)&lnb[cb];
    ushort4 outv;
    outv.x = f2bu(fmaxf((o0 - mu) * rstd * w4.x + b4.x, 0.f));
    outv.y = f2bu(fmaxf((o1 - mu) * rstd * w4.y + b4.y, 0.f));
    outv.z = f2bu(fmaxf((o2 - mu) * rstd * w4.z + b4.z, 0.f));
    outv.w = f2bu(fmaxf((o3 - mu) * rstd * w4.w + b4.w, 0.f));
    *(ushort4*)&hout[(size_t)node * H + cb] = outv;
}

// ---------------------------------------------------------------------------
// Pool BEFORE projection (linearity reorder). Stage 1: segmented atomic sums.
// ---------------------------------------------------------------------------
__global__ __launch_bounds__(256) void k_pool_sum(
    const unsigned short* __restrict__ hb, const int* __restrict__ batch,
    float* __restrict__ pooled, int N) {
    int c = threadIdx.x;
    int chunk = (N + gridDim.x - 1) / gridDim.x;
    int n0 = blockIdx.x * chunk;
    int n1 = min(n0 + chunk, N);
    if (n0 >= n1) return;
    float acc = 0.f;
    int cur = batch[n0];
    for (int n = n0; n < n1; n++) {
        int g = batch[n];
        if (g != cur) {
            atomicAdd(&pooled[cur * H + c], acc);
            acc = 0.f; cur = g;
        }
        acc += b2f(hb[(size_t)n * H + c]);
    }
    atomicAdd(&pooled[cur * H + c], acc);
}

// Stage 2: out[g] = (pooled[g]/cnt) @ lin_W + lin_b
__global__ __launch_bounds__(256) void k_lin_pool(
    const float* __restrict__ pooled, const int* __restrict__ batch,
    const float* __restrict__ linW, const float* __restrict__ linb,
    float* __restrict__ out, int N) {
    __shared__ float row[H];
    __shared__ int s_lo, s_hi;
    int g = blockIdx.x, c = threadIdx.x;
    if (c == 0) {
        int lo = 0, hi = N;
        while (lo < hi) { int mid = (lo + hi) >> 1; if (batch[mid] < g) lo = mid + 1; else hi = mid; }
        s_lo = lo;
    }
    if (c == 1) {
        int lo = 0, hi = N;
        while (lo < hi) { int mid = (lo + hi) >> 1; if (batch[mid] < g + 1) lo = mid + 1; else hi = mid; }
        s_hi = lo;
    }
    __syncthreads();
    int cnt = s_hi - s_lo;
    float scale = (cnt > 0) ? 1.f / (float)cnt : 0.f;
    row[c] = pooled[g * H + c] * scale;
    __syncthreads();
    float acc = (cnt > 0) ? linb[c] : 0.f;
#pragma unroll 8
    for (int k = 0; k < H; k++) acc = fmaf(row[k], linW[k * H + c], acc);
    out[g * H + c] = acc;
}

// ---------------------------------------------------------------------------
extern "C" void kernel_launch(void* const* d_in, const int* in_sizes, int n_in,
                              void* d_out, int out_size, void* d_ws, size_t ws_size,
                              hipStream_t stream) {
    const float* x        = (const float*)d_in[0];
    const int*   ei       = (const int*)d_in[1];
    const float* eattr    = (const float*)d_in[2];
    const int*   batch    = (const int*)d_in[3];
    const float* W_l0     = (const float*)d_in[4];
    const float* W_r0     = (const float*)d_in[5];
    const float* W_l      = (const float*)d_in[6];
    const float* W_r      = (const float*)d_in[7];
    const float* b_l      = (const float*)d_in[8];
    const float* b_r      = (const float*)d_in[9];
    const float* W_e      = (const float*)d_in[10];
    const float* att      = (const float*)d_in[11];
    const float* bias     = (const float*)d_in[12];
    const float* ln_w     = (const float*)d_in[13];
    const float* ln_b     = (const float*)d_in[14];
    const float* lin_W    = (const float*)d_in[15];
    const float* lin_b    = (const float*)d_in[16];

    const int N = in_sizes[0] / 23;          // 20000
    const int E = in_sizes[1] / 2;           // 320000
    const int G = out_size / H;              // 64
    const int L = 4;

    // workspace layout
    char* p = (char*)d_ws;
    unsigned short* hlb = (unsigned short*)p;     p += (size_t)N * H * 2;
    unsigned short* hrb = (unsigned short*)p;     p += (size_t)N * H * 2;
    float4* erec = (float4*)p;                    p += (size_t)E * 32;
    unsigned short* hb = (unsigned short*)p;      p += (size_t)NPAD * H * 2;
    __hip_bfloat16* xb  = (__hip_bfloat16*)p;     p += (size_t)NPAD * 32 * 2;
    __hip_bfloat16* w0t = (__hip_bfloat16*)p;     p += (size_t)2 * 256 * 32 * 2;
    __hip_bfloat16* wbig = (__hip_bfloat16*)p;    p += (size_t)6 * 65536 * 2;
    float* loop_attr = (float*)p;                 p += (size_t)N * 8 * 4;
    float* pooled = (float*)p;                    p += (size_t)G * H * 4;
    int* deg      = (int*)p;                      p += (size_t)N * 4;
    int* row_ptr  = (int*)p;                      p += (size_t)(N + 1) * 4;
    int* cursor   = (int*)p;                      p += (size_t)N * 4;
    int* bsum     = (int*)p;                      p += (size_t)256 * 4;

    __hip_bfloat16* Wl0t = w0t;
    __hip_bfloat16* Wr0t = w0t + 8192;
    __hip_bfloat16* Wlt  = wbig;
    __hip_bfloat16* Wrt  = wbig + (size_t)3 * 65536;

    int tb = 256;
    int conv_total = NPAD * 32 + 16384 + 6 * 65536 + N + 16384 + (NPAD - N) * 128;
    k_conv_all<<<(conv_total + tb - 1) / tb, tb, 0, stream>>>(
        x, W_l0, W_r0, W_l, W_r, xb, w0t, wbig, deg, pooled,
        (unsigned int*)(hb + (size_t)N * H), N);

    k_edge_hist<<<(E + tb - 1) / tb, tb, 0, stream>>>(ei, deg, E);
    int nb = (N + 255) / 256;
    k_scan1<<<nb, 256, 0, stream>>>(deg, row_ptr, bsum, N);
    k_scan2<<<1, 256, 0, stream>>>(bsum, nb);
    k_scan3<<<nb, 256, 0, stream>>>(row_ptr, cursor, bsum, N, E);
    k_scatter<<<(E + tb - 1) / tb, tb, 0, stream>>>(ei, eattr, cursor, erec, E);
    k_loop_mean<<<(N + 3) / 4, 256, 0, stream>>>(row_ptr, erec, loop_attr, N);

    dim3 gdual(4, NPAD / 128), blk(256);

    for (int l = 0; l < L; l++) {
        const __hip_bfloat16* A  = (l == 0) ? xb : (const __hip_bfloat16*)hb;
        const __hip_bfloat16* Wl = (l == 0) ? Wl0t : (Wlt + (size_t)(l - 1) * 65536);
        const __hip_bfloat16* Wr = (l == 0) ? Wr0t : (Wrt + (size_t)(l - 1) * 65536);
        if (l == 0)
            k_gemm_mfma<32><<<gdual, blk, 0, stream>>>(A, N, Wl, b_l + l * H, hlb,
                                                       Wr, b_r + l * H, hrb);
        else
            k_gemm_mfma<256><<<gdual, blk, 0, stream>>>(A, N, Wl, b_l + l * H, hlb,
                                                        Wr, b_r + l * H, hrb);
        k_gat<<<N, 64, 0, stream>>>(hlb, hrb, row_ptr, erec, loop_attr,
                                    W_e + (size_t)l * EDIM * H, att + l * H,
                                    bias + l * H, ln_w + l * H, ln_b + l * H, hb, N);
    }

    // pool-then-project (linearity reorder): mean(h) @ lin_W + lin_b
    k_pool_sum<<<256, 256, 0, stream>>>(hb, batch, pooled, N);
    k_lin_pool<<<G, 256, 0, stream>>>(pooled, batch, lin_W, lin_b, (float*)d_out, N);
}